// Round 12
// baseline (74.308 us; speedup 1.0000x reference)
//
#include <hip/hip_runtime.h>

#define NB 8
#define NS 2048
#define ND 1024
#define NE 8

typedef unsigned short ushort_t;
typedef __attribute__((ext_vector_type(8))) short bf16x8;
typedef __attribute__((ext_vector_type(4))) float f32x4;

__device__ __forceinline__ unsigned short f2bf(float f) {
    union { float f; unsigned int u; } x; x.f = f;
    unsigned int u = x.u + 0x7fffu + ((x.u >> 16) & 1u);
    return (unsigned short)(u >> 16);
}

__device__ __forceinline__ unsigned pk2(float a, float b) {
    return (unsigned)f2bf(a) | ((unsigned)f2bf(b) << 16);
}

__device__ __forceinline__ void gload16(const void* g, void* l) {
    __builtin_amdgcn_global_load_lds(
        (const __attribute__((address_space(1))) unsigned int*)g,
        (__attribute__((address_space(3))) unsigned int*)l, 16, 0, 0);
}

// local top-k gate coefs for one batch row (deterministic tie-break = first index)
__device__ __forceinline__ void coef_local(const float* __restrict__ scores,
                                           int b, int k, float* cf) {
    float s[NE];
#pragma unroll
    for (int e = 0; e < NE; ++e) s[e] = scores[b * NE + e];
    bool sel[NE];
#pragma unroll
    for (int e = 0; e < NE; ++e) sel[e] = false;
    float sum = 0.f;
    for (int j = 0; j < k; ++j) {
        int best = 0; float bv = -3.4e38f;
#pragma unroll
        for (int e = 0; e < NE; ++e)
            if (!sel[e] && s[e] > bv) { bv = s[e]; best = e; }
        sel[best] = true; sum += bv;
    }
    float scale = 1.f / (sum + 1e-8f);
#pragma unroll
    for (int e = 0; e < NE; ++e) cf[e] = sel[e] ? scale * s[e] : 0.f;
}

// ====== fused prep: combine (2048 blk) | bias (32) | routing (1) ======
// (convert removed -- x is cast in-GEMM now)
__global__ void prep_kernel(const float* __restrict__ scores,
                            const float* __restrict__ W,
                            const float* __restrict__ eb,
                            const int* __restrict__ kp,
                            ushort_t* __restrict__ wct,
                            float* __restrict__ bias,
                            float* __restrict__ counts) {
    __shared__ float tile[64][65];
    __shared__ int selS[NB][NE];
    int bid = blockIdx.x;
    int t = threadIdx.x;

    if (bid < 2048) {
        int b = bid >> 8;
        int f0 = (bid & 15) * 64, d0 = ((bid >> 4) & 15) * 64;
        float cf[NE];
        coef_local(scores, b, kp[0], cf);
        int lr = t >> 4;
        int lc = (t & 15) * 4;
        float4 acc[4];
#pragma unroll
        for (int it = 0; it < 4; ++it) acc[it] = make_float4(0.f, 0.f, 0.f, 0.f);
#pragma unroll
        for (int e = 0; e < NE; ++e) {
            float c = cf[e];
            if (c != 0.f) {
                const float* We = W + ((size_t)e * ND * ND);
#pragma unroll
                for (int it = 0; it < 4; ++it) {
                    int d = d0 + lr + it * 16;
                    float4 v = *(const float4*)(We + (size_t)d * ND + f0 + lc);
                    acc[it].x += c * v.x; acc[it].y += c * v.y;
                    acc[it].z += c * v.z; acc[it].w += c * v.w;
                }
            }
        }
#pragma unroll
        for (int it = 0; it < 4; ++it) {
            int r = lr + it * 16;
            tile[r][lc + 0] = acc[it].x; tile[r][lc + 1] = acc[it].y;
            tile[r][lc + 2] = acc[it].z; tile[r][lc + 3] = acc[it].w;
        }
        __syncthreads();
        int dl = t & 63;
        int frow = t >> 6;
        ushort_t* dst = wct + (size_t)b * ND * ND + (size_t)f0 * ND + d0 + dl;
#pragma unroll
        for (int it = 0; it < 16; ++it) {
            int f = frow + it * 4;
            dst[(size_t)f * ND] = f2bf(tile[dl][f]);
        }
    } else if (bid < 2080) {
        int i = bid - 2048;
        int b = i >> 2, f = (i & 3) * 256 + t;
        float cf[NE];
        coef_local(scores, b, kp[0], cf);
        float acc = 0.f;
#pragma unroll
        for (int e = 0; e < NE; ++e)
            if (cf[e] != 0.f) acc += cf[e] * eb[e * ND + f];
        bias[b * ND + f] = acc;
    } else {
        int k = kp[0];
        if (t < NB) {
            float s[NE];
#pragma unroll
            for (int e = 0; e < NE; ++e) s[e] = scores[t * NE + e];
            bool sel[NE];
#pragma unroll
            for (int e = 0; e < NE; ++e) sel[e] = false;
            for (int j = 0; j < k; ++j) {
                int best = 0; float bv = -3.4e38f;
#pragma unroll
                for (int e = 0; e < NE; ++e)
                    if (!sel[e] && s[e] > bv) { bv = s[e]; best = e; }
                sel[best] = true;
            }
#pragma unroll
            for (int e = 0; e < NE; ++e) selS[t][e] = sel[e] ? 1 : 0;
        }
        __syncthreads();
        if (t < NE) {
            int c = 0;
#pragma unroll
            for (int b = 0; b < NB; ++b) c += selS[b][t];
            counts[t] = (float)c;
        }
    }
}

// ====== R9 base (256x128, BK=32, 3-buf, 2 blocks/CU) + fused fp32->bf16 A-staging ======
// A: fp32 x -> regs (issued late iter t-1, full-tile runway) -> cvt_pk -> swizzled
// ds_write after MFMA. B: global_load_lds, counted vmcnt. One barrier/iter.
__global__ __launch_bounds__(512, 4) void gemm_kernel(const float* __restrict__ x,
                                                      const ushort_t* __restrict__ wct,
                                                      const float* __restrict__ bias,
                                                      float* __restrict__ out) {
    __shared__ ushort_t ldsA[3][256 * 32];   // 48 KiB
    __shared__ ushort_t ldsB[3][128 * 32];   // 24 KiB

    int bid = blockIdx.x;
    int b = bid & 7;                 // batch -> XCD (round-robin % 8)
    int tile = bid >> 3;             // 0..63
    int m0 = (tile >> 3) * 256;      // 8 M-tiles
    int n0 = (tile & 7) * 128;       // 8 N-tiles
    const ushort_t* Bt = wct + ((size_t)b * ND * ND) + (size_t)n0 * ND;

    int t = threadIdx.x, lane = t & 63, wave = t >> 6;
    int wm = wave >> 1, wn = wave & 1;          // 4 x 2 wave grid, wave tile 64x64
    int fr = lane & 15, fq = lane >> 4;

    // ---- B staging source (pre-swizzled slot; LDS dest linear DMA) ----
    int srow = t >> 2;                               // 0..127
    int slotg = (t & 3) ^ ((srow >> 1) & 3);
    const ushort_t* sB = Bt + (size_t)srow * ND + slotg * 8;
    int ldstB = t * 8;

    // ---- A fused staging: thread -> row ar (0..255), half ah; swizzled ds_write ----
    int ar = t >> 1, ah = t & 1;
    const float* xA = x + ((size_t)b * NS * ND) + (size_t)(m0 + ar) * ND + ah * 16;
    int swA = (ar >> 1) & 3;
    int woff0 = ar * 32 + ((2 * ah) ^ swA) * 8;      // ushort offsets
    int woff1 = ar * 32 + ((2 * ah + 1) ^ swA) * 8;

    // ---- read-side fragment byte offsets (R7/R9 HW-verified 0-conflict swizzle) ----
    int swzb = (fq ^ ((fr >> 1) & 3)) * 16;
    int aoff[4], boff[4];
#pragma unroll
    for (int mi = 0; mi < 4; ++mi) aoff[mi] = (wm * 64 + mi * 16 + fr) * 64 + swzb;
#pragma unroll
    for (int nj = 0; nj < 4; ++nj) boff[nj] = (wn * 64 + nj * 16 + fr) * 64 + swzb;

    f32x4 acc[4][4];
#pragma unroll
    for (int i = 0; i < 4; ++i)
#pragma unroll
        for (int j = 0; j < 4; ++j) acc[i][j] = (f32x4){0.f, 0.f, 0.f, 0.f};

    const int NT = ND / 32;   // 32 K-tiles

    float4 rA0, rA1, rA2, rA3;
#define LOAD_A(kt) do { \
    const float* xp = xA + (kt) * 32; \
    rA0 = *(const float4*)(xp);      rA1 = *(const float4*)(xp + 4); \
    rA2 = *(const float4*)(xp + 8);  rA3 = *(const float4*)(xp + 12); \
} while (0)
#define CVT_WRITE(buf) do { \
    uint4 o0, o1; \
    o0.x = pk2(rA0.x, rA0.y); o0.y = pk2(rA0.z, rA0.w); \
    o0.z = pk2(rA1.x, rA1.y); o0.w = pk2(rA1.z, rA1.w); \
    o1.x = pk2(rA2.x, rA2.y); o1.y = pk2(rA2.z, rA2.w); \
    o1.z = pk2(rA3.x, rA3.y); o1.w = pk2(rA3.z, rA3.w); \
    *(uint4*)(&ldsA[buf][woff0]) = o0; \
    *(uint4*)(&ldsA[buf][woff1]) = o1; \
} while (0)

    // ---- prologue ----
    LOAD_A(0);                                         // A0 -> regs
    gload16(sB, &ldsB[0][ldstB]);                      // B0
    gload16(sB + 32, &ldsB[1][ldstB]);                 // B1
    asm volatile("s_waitcnt vmcnt(2)" ::: "memory");   // A0 landed
    CVT_WRITE(0);                                      // A0 -> ldsA[0]
    LOAD_A(1);                                         // A1 -> regs
    asm volatile("s_waitcnt vmcnt(5)" ::: "memory");   // B0 landed
    asm volatile("s_waitcnt lgkmcnt(0)" ::: "memory"); // A0 writes drained
    __builtin_amdgcn_s_barrier();

    for (int kt = 0; kt < NT; ++kt) {
        int cur = kt; while (cur >= 3) cur -= 3;       // kt % 3 (kt small; compiler folds)
        const char* lA = (const char*)&ldsA[cur][0];
        const char* lB = (const char*)&ldsB[cur][0];
        int nb = cur + 1; if (nb == 3) nb = 0;         // (kt+1) % 3
        int sq = cur + 2; if (sq >= 3) sq -= 3;        // (kt+2) % 3

        // top: B(t+2) DMA (stays in flight across this iter's barrier)
        if (kt + 2 < NT) gload16(sB + (kt + 2) * 32, &ldsB[sq][ldstB]);

        bf16x8 af[4], bf[4];
#pragma unroll
        for (int nj = 0; nj < 4; ++nj) bf[nj] = *(const bf16x8*)(lB + boff[nj]);
#pragma unroll
        for (int mi = 0; mi < 4; ++mi) af[mi] = *(const bf16x8*)(lA + aoff[mi]);
        __builtin_amdgcn_sched_barrier(0);
        asm volatile("s_waitcnt lgkmcnt(0)" ::: "memory");
        __builtin_amdgcn_sched_barrier(0);
        __builtin_amdgcn_s_setprio(1);
#pragma unroll
        for (int mi = 0; mi < 4; ++mi)
#pragma unroll
            for (int nj = 0; nj < 4; ++nj)
                acc[mi][nj] = __builtin_amdgcn_mfma_f32_16x16x32_bf16(af[mi], bf[nj], acc[mi][nj], 0, 0, 0);
        __builtin_amdgcn_s_setprio(0);
        __builtin_amdgcn_sched_barrier(0);

        if (kt + 1 < NT) {
            // gate A(t+1) regs: leave only B(t+2) (if issued) in flight
            if (kt + 2 < NT) asm volatile("s_waitcnt vmcnt(1)" ::: "memory");
            else             asm volatile("s_waitcnt vmcnt(0)" ::: "memory");
            __builtin_amdgcn_sched_barrier(0);
            CVT_WRITE(nb);                             // A(t+1) -> ldsA[(t+1)%3]
            if (kt + 2 < NT) LOAD_A(kt + 2);           // A(t+2) -> regs (runway = 1 tile)
            __builtin_amdgcn_sched_barrier(0);
            asm volatile("s_waitcnt lgkmcnt(0)" ::: "memory");   // writes drained
            __builtin_amdgcn_s_barrier();
        }
    }

#undef LOAD_A
#undef CVT_WRITE

    // ---- epilogue: bias + fp32 store ----
    const float* bs = bias + b * ND;
    float* O = out + ((size_t)b * NS * ND);
#pragma unroll
    for (int mi = 0; mi < 4; ++mi) {
        int row = m0 + wm * 64 + mi * 16 + fq * 4;
#pragma unroll
        for (int nj = 0; nj < 4; ++nj) {
            int col = n0 + wn * 64 + nj * 16 + fr;
            float bv = bs[col];
            f32x4 v = acc[mi][nj];
#pragma unroll
            for (int r = 0; r < 4; ++r)
                O[(size_t)(row + r) * ND + col] = v[r] + bv;
        }
    }
}

extern "C" void kernel_launch(void* const* d_in, const int* in_sizes, int n_in,
                              void* d_out, int out_size, void* d_ws, size_t ws_size,
                              hipStream_t stream) {
    const float* x      = (const float*)d_in[0];
    const float* scores = (const float*)d_in[1];
    const float* Wx     = (const float*)d_in[2];
    const float* eb     = (const float*)d_in[3];
    const int*   kp     = (const int*)d_in[4];
    float* out = (float*)d_out;
    char* ws = (char*)d_ws;

    float*    bias  = (float*)(ws + 1024);
    ushort_t* wct   = (ushort_t*)(ws + 65536);
    float*    counts = out + (size_t)NB * NS * ND;

    prep_kernel<<<2081, 256, 0, stream>>>(scores, Wx, eb, kp, wct, bias, counts);
    gemm_kernel<<<512, 512, 0, stream>>>(x, wct, bias, out);
}